// Round 12
// baseline (311.156 us; speedup 1.0000x reference)
//
#include <hip/hip_runtime.h>
#include <math.h>
#include <float.h>

#define BATCH 4096
#define CAP   32768

typedef _Float16 f16;
typedef _Float16 f16x8 __attribute__((ext_vector_type(8)));
typedef float    f32x4 __attribute__((ext_vector_type(4)));

__device__ __forceinline__ f32x4 MF(f16x8 a, f16x8 b, f32x4 c) {
    return __builtin_amdgcn_mfma_f32_16x16x32_f16(a, b, c, 0, 0, 0);
}

// ---------------- fused prep: projections + mem_keys split + winner init ----------------
__global__ __launch_bounds__(256) void prep_kernel(
    const float* __restrict__ keys, const float* __restrict__ query,
    const float* __restrict__ Wk, const float* __restrict__ bk,
    const float* __restrict__ Wv, const float* __restrict__ bv,
    const float* __restrict__ mk,
    f16* __restrict__ kph, f16* __restrict__ kpl,
    f16* __restrict__ svh,
    f16* __restrict__ qph, f16* __restrict__ qpl,
    f16* __restrict__ mkh, f16* __restrict__ mkl,
    int* __restrict__ winner)
{
    int bx = blockIdx.x;
    int tid = threadIdx.x;
    if (bx >= 768) {
        int i = (bx - 768)*256 + tid;    // CAP*64 elements
        float x = mk[i];
        f16 h = (f16)x;
        mkh[i] = h;
        mkl[i] = (f16)((x - (float)h) * 2048.0f);
        if (i < CAP) winner[i] = -1;
        return;
    }
    int job = bx >> 8;   // 0: keys@Wk->kp (scaled lo), 1: query@Wv->sv (hi only), 2: query@Wk->qp
    const float *in, *W, *b; f16 *oh, *ol; bool scaled;
    if (job == 0)      { in = keys;  W = Wk; b = bk; oh = kph; ol = kpl;     scaled = true;  }
    else if (job == 1) { in = query; W = Wv; b = bv; oh = svh; ol = nullptr; scaled = false; }
    else               { in = query; W = Wk; b = bk; oh = qph; ol = qpl;     scaled = false; }

    __shared__ float Wl[64*65];
    __shared__ float inl[16*65];
    __shared__ float bl[64];
    int row0 = (bx & 255) * 16;
    for (int i = tid; i < 4096; i += 256) { int r = i >> 6, c = i & 63; Wl[r*65+c] = W[i]; }
    for (int i = tid; i < 1024; i += 256) { int r = i >> 6, c = i & 63; inl[r*65+c] = in[(row0+r)*64 + c]; }
    if (tid < 64) bl[tid] = b[tid];
    __syncthreads();

    int col = tid & 63;
    int rq  = tid >> 6;
    #pragma unroll
    for (int q = 0; q < 4; ++q) {
        int r = rq*4 + q;
        float acc = bl[col];
        #pragma unroll
        for (int k = 0; k < 64; ++k) acc += inl[r*65+k] * Wl[col*65+k];
        float t = tanhf(acc);
        f16 h = (f16)t;
        oh[(row0+r)*64 + col] = h;
        if (ol) {
            float lo = t - (float)h;
            if (scaled) lo *= 2048.0f;
            ol[(row0+r)*64 + col] = (f16)lo;
        }
    }
}

// ---------------- sim: staged + prefetch, 32-row waves, 3-term; partial argmax ----------------
// grid (32 sb x 1024 slots, 32 rb x 128 rows) = 1024 blocks = 4/CU exact
__global__ __launch_bounds__(256, 4) void sim_kernel(
    const f16* __restrict__ Aph, const f16* __restrict__ Apl,
    const f16* __restrict__ Bph, const f16* __restrict__ Bpl,
    float* __restrict__ bestv, int* __restrict__ besti)
{
    __shared__ __align__(16) f16 Bh[64*72], Bl[64*72];
    int tid = threadIdx.x, l = tid & 63, w = tid >> 6;
    int sb = blockIdx.x, rb = blockIdx.y;
    int row0 = rb*128 + w*32;
    int lr = l & 15, lg = l >> 4;
    int sl0 = tid >> 3, ch = tid & 7;

    f16x8 ah[2][2], al[2][2];
    #pragma unroll
    for (int i = 0; i < 2; ++i)
        #pragma unroll
        for (int t = 0; t < 2; ++t) {
            size_t o = (size_t)(row0 + i*16 + lr)*64 + t*32 + lg*8;
            ah[i][t] = *(const f16x8*)&Aph[o];
            al[i][t] = *(const f16x8*)&Apl[o];
        }
    float bvv[2][4]; int bii[2][4];
    #pragma unroll
    for (int i = 0; i < 2; ++i)
        #pragma unroll
        for (int j = 0; j < 4; ++j) { bvv[i][j] = -FLT_MAX; bii[i][j] = 0; }

    f16x8 pb[2][2];
    {
        int s0 = sb*1024;
        pb[0][0] = *(const f16x8*)&Bph[(size_t)(s0+sl0)*64 + ch*8];
        pb[0][1] = *(const f16x8*)&Bpl[(size_t)(s0+sl0)*64 + ch*8];
        pb[1][0] = *(const f16x8*)&Bph[(size_t)(s0+sl0+32)*64 + ch*8];
        pb[1][1] = *(const f16x8*)&Bpl[(size_t)(s0+sl0+32)*64 + ch*8];
    }

    for (int st = 0; st < 16; ++st) {
        int s0 = sb*1024 + st*64;
        __syncthreads();
        *(f16x8*)&Bh[sl0*72 + ch*8]      = pb[0][0];
        *(f16x8*)&Bl[sl0*72 + ch*8]      = pb[0][1];
        *(f16x8*)&Bh[(sl0+32)*72 + ch*8] = pb[1][0];
        *(f16x8*)&Bl[(sl0+32)*72 + ch*8] = pb[1][1];
        __syncthreads();
        if (st + 1 < 16) {
            int sn = s0 + 64;
            pb[0][0] = *(const f16x8*)&Bph[(size_t)(sn+sl0)*64 + ch*8];
            pb[0][1] = *(const f16x8*)&Bpl[(size_t)(sn+sl0)*64 + ch*8];
            pb[1][0] = *(const f16x8*)&Bph[(size_t)(sn+sl0+32)*64 + ch*8];
            pb[1][1] = *(const f16x8*)&Bpl[(size_t)(sn+sl0+32)*64 + ch*8];
        }
        #pragma unroll
        for (int cf = 0; cf < 4; ++cf) {
            int c0 = cf*16;
            f16x8 bh[2], bl2[2];
            #pragma unroll
            for (int t = 0; t < 2; ++t) {
                bh[t]  = *(const f16x8*)&Bh[(c0+lr)*72 + t*32 + lg*8];
                bl2[t] = *(const f16x8*)&Bl[(c0+lr)*72 + t*32 + lg*8];
            }
            f32x4 z = {0.f,0.f,0.f,0.f};
            f32x4 aA[2] = {z,z}, aB[2] = {z,z};
            #pragma unroll
            for (int i = 0; i < 2; ++i)
                #pragma unroll
                for (int t = 0; t < 2; ++t) {
                    aA[i] = MF(ah[i][t], bh[t],  aA[i]);
                    aB[i] = MF(ah[i][t], bl2[t], aB[i]);
                    aB[i] = MF(al[i][t], bh[t],  aB[i]);
                }
            int slot = s0 + c0 + lr;
            #pragma unroll
            for (int i = 0; i < 2; ++i)
                #pragma unroll
                for (int j = 0; j < 4; ++j) {
                    float v = aA[i][j] + aB[i][j]*(1.0f/2048.0f);
                    if (v > bvv[i][j]) { bvv[i][j] = v; bii[i][j] = slot; }
                }
        }
    }
    #pragma unroll
    for (int m = 1; m < 16; m <<= 1)
        #pragma unroll
        for (int i = 0; i < 2; ++i)
            #pragma unroll
            for (int j = 0; j < 4; ++j) {
                float ov = __shfl_xor(bvv[i][j], m);
                int   oi = __shfl_xor(bii[i][j], m);
                if (ov > bvv[i][j] || (ov == bvv[i][j] && oi < bii[i][j])) { bvv[i][j] = ov; bii[i][j] = oi; }
            }
    if (lr == 0) {
        #pragma unroll
        for (int i = 0; i < 2; ++i)
            #pragma unroll
            for (int j = 0; j < 4; ++j) {
                int r = row0 + i*16 + lg*4 + j;
                bestv[r*32 + sb] = bvv[i][j];
                besti[r*32 + sb] = bii[i][j];
            }
    }
}

// ---------------- argmax combine + winner scatter ----------------
__global__ void argmax_scatter_kernel(const float* __restrict__ bestv,
                                      const int* __restrict__ besti,
                                      int* __restrict__ winner)
{
    int r = blockIdx.x*256 + threadIdx.x;
    if (r >= BATCH) return;
    float bv = bestv[r*32]; int bi = besti[r*32];
    #pragma unroll
    for (int sb = 1; sb < 32; ++sb) {
        float v = bestv[r*32+sb]; int ii = besti[r*32+sb];
        if (v > bv || (v == bv && ii < bi)) { bv = v; bi = ii; }
    }
    atomicMax(&winner[bi], r);
}

// ---------------- build new_keys hi plane + transposed new_values (hi only) ----------------
__global__ __launch_bounds__(256) void build_kernel(
    const int* __restrict__ winner,
    const f16* __restrict__ kph,
    const f16* __restrict__ svh,
    const float* __restrict__ mk, const float* __restrict__ mv,
    f16* __restrict__ nkh,
    f16* __restrict__ nvTh)
{
    __shared__ __align__(16) f16 Lh[64*72];
    int tid = threadIdx.x;
    int s0 = blockIdx.x*64;
    #pragma unroll
    for (int c = 0; c < 2; ++c) {
        int task = tid + 256*c; int sl = task >> 3, ch = task & 7;
        int s = s0 + sl; int w = winner[s];
        f16x8 hk, hv;
        if (w >= 0) {
            hk = *(const f16x8*)&kph[(size_t)w*64 + ch*8];
            hv = *(const f16x8*)&svh[(size_t)w*64 + ch*8];
        } else {
            #pragma unroll
            for (int q = 0; q < 8; ++q) {
                hk[q] = (f16)mk[(size_t)s*64 + ch*8 + q];
                hv[q] = (f16)mv[(size_t)s*64 + ch*8 + q];
            }
        }
        *(f16x8*)&nkh[(size_t)s*64 + ch*8] = hk;
        *(f16x8*)&Lh[sl*72 + ch*8] = hv;
    }
    __syncthreads();
    int v = tid >> 2, sc = (tid & 3)*16;
    f16x8 a, b2;
    #pragma unroll
    for (int q = 0; q < 8; ++q) { a[q] = Lh[(sc+q)*72 + v]; b2[q] = Lh[(sc+8+q)*72 + v]; }
    *(f16x8*)&nvTh[(size_t)v*CAP + s0 + sc]     = a;
    *(f16x8*)&nvTh[(size_t)v*CAP + s0 + sc + 8] = b2;
}

// ---------------- pass1: denominator only. hh-only logits; S = sum exp(v) ----------------
// grid (64 sb x 512 slots, 16 rb x 256 rows) = 1024 blocks = 4/CU exact; 64-row waves
__global__ __launch_bounds__(256, 4) void logits_stats_kernel(
    const f16* __restrict__ Aph,
    const f16* __restrict__ Bph,
    float* __restrict__ s_part)
{
    __shared__ __align__(16) f16 Bh[64*72];
    int tid = threadIdx.x, l = tid & 63, w = tid >> 6;
    int sb = blockIdx.x, rb = blockIdx.y;
    int row0 = rb*256 + w*64;
    int lr = l & 15, lg = l >> 4;
    int sl0 = tid >> 3, ch = tid & 7;

    f16x8 ah[4][2];
    #pragma unroll
    for (int i = 0; i < 4; ++i)
        #pragma unroll
        for (int t = 0; t < 2; ++t)
            ah[i][t] = *(const f16x8*)&Aph[(size_t)(row0 + i*16 + lr)*64 + t*32 + lg*8];

    float ssum[4][4];
    #pragma unroll
    for (int i = 0; i < 4; ++i)
        #pragma unroll
        for (int j = 0; j < 4; ++j) ssum[i][j] = 0.f;

    f16x8 pb[2];
    {
        int s0 = sb*512;
        pb[0] = *(const f16x8*)&Bph[(size_t)(s0+sl0)*64 + ch*8];
        pb[1] = *(const f16x8*)&Bph[(size_t)(s0+sl0+32)*64 + ch*8];
    }

    for (int st = 0; st < 8; ++st) {
        int s0 = sb*512 + st*64;
        __syncthreads();
        *(f16x8*)&Bh[sl0*72 + ch*8]      = pb[0];
        *(f16x8*)&Bh[(sl0+32)*72 + ch*8] = pb[1];
        __syncthreads();
        if (st + 1 < 8) {
            int sn = s0 + 64;
            pb[0] = *(const f16x8*)&Bph[(size_t)(sn+sl0)*64 + ch*8];
            pb[1] = *(const f16x8*)&Bph[(size_t)(sn+sl0+32)*64 + ch*8];
        }
        #pragma unroll
        for (int cf = 0; cf < 4; ++cf) {
            int c0 = cf*16;
            f16x8 bh[2];
            #pragma unroll
            for (int t = 0; t < 2; ++t)
                bh[t] = *(const f16x8*)&Bh[(c0+lr)*72 + t*32 + lg*8];
            f32x4 z = {0.f,0.f,0.f,0.f};
            f32x4 acc[4] = {z,z,z,z};
            #pragma unroll
            for (int i = 0; i < 4; ++i) {
                acc[i] = MF(ah[i][0], bh[0], acc[i]);
                acc[i] = MF(ah[i][1], bh[1], acc[i]);
            }
            #pragma unroll
            for (int i = 0; i < 4; ++i)
                #pragma unroll
                for (int j = 0; j < 4; ++j)
                    ssum[i][j] += __expf(acc[i][j]);
        }
    }
    #pragma unroll
    for (int m = 1; m < 16; m <<= 1)
        #pragma unroll
        for (int i = 0; i < 4; ++i)
            #pragma unroll
            for (int j = 0; j < 4; ++j)
                ssum[i][j] += __shfl_xor(ssum[i][j], m);
    if (lr == 0) {
        #pragma unroll
        for (int i = 0; i < 4; ++i)
            #pragma unroll
            for (int j = 0; j < 4; ++j) {
                int r = row0 + i*16 + lg*4 + j;
                s_part[r*64 + sb] = ssum[i][j];
            }
    }
}

// ---------------- pass2: K/V staged + prefetch, wave-private P, 32-row waves ----------------
// grid (32 sb x 1024 slots, 32 rb x 128 rows) = 1024 blocks = 4/CU exact
__global__ __launch_bounds__(256, 4) void pass2_kernel(
    const f16* __restrict__ qph, const f16* __restrict__ qpl,
    const f16* __restrict__ nkh,
    const f16* __restrict__ nvTh,
    const float* __restrict__ s_part,
    float* __restrict__ att, float* __restrict__ ret_part)
{
    __shared__ __align__(16) f16 Kh[64*72];
    __shared__ __align__(16) f16 Vh[64*72];
    __shared__ __align__(16) f16 Ph[4][32*72];   // wave-private P
    __shared__ float iSl[128];
    int tid = threadIdx.x, l = tid & 63, w = tid >> 6;
    int sb = blockIdx.x, rb = blockIdx.y;
    int brow0 = rb*128;
    int wrow0 = brow0 + w*32;
    int lr = l & 15, lg = l >> 4;
    int sl0 = tid >> 3, ch = tid & 7;
    f16* Pw = &Ph[w][0];

    // prologue: per-row denominator (2 threads/row)
    {
        int r_loc = tid >> 1, half = tid & 1;
        const float4* p = (const float4*)(s_part + (size_t)(brow0 + r_loc)*64 + half*32);
        float S = 0.f;
        #pragma unroll
        for (int q = 0; q < 8; ++q) {
            float4 v = p[q];
            S += (v.x + v.y) + (v.z + v.w);
        }
        S += __shfl_xor(S, 1);
        if (!half) iSl[r_loc] = 1.0f / S;
    }

    f16x8 ah[2][2], al[2][2];
    #pragma unroll
    for (int i = 0; i < 2; ++i)
        #pragma unroll
        for (int t = 0; t < 2; ++t) {
            size_t o = (size_t)(wrow0 + i*16 + lr)*64 + t*32 + lg*8;
            ah[i][t] = *(const f16x8*)&qph[o];
            al[i][t] = *(const f16x8*)&qpl[o];
        }
    f16x8 pk[2], pv[2];
    {
        int s0g = sb*1024;
        pk[0] = *(const f16x8*)&nkh[(size_t)(s0g+sl0)*64 + ch*8];
        pk[1] = *(const f16x8*)&nkh[(size_t)(s0g+sl0+32)*64 + ch*8];
        pv[0] = *(const f16x8*)&nvTh[(size_t)sl0*CAP + s0g + ch*8];
        pv[1] = *(const f16x8*)&nvTh[(size_t)(sl0+32)*CAP + s0g + ch*8];
    }
    __syncthreads();   // iSl visible
    float iS[2][4];
    #pragma unroll
    for (int i = 0; i < 2; ++i)
        #pragma unroll
        for (int j = 0; j < 4; ++j)
            iS[i][j] = iSl[w*32 + i*16 + lg*4 + j];

    f32x4 z = {0.f,0.f,0.f,0.f};
    f32x4 pacc[2][4] = {{z,z,z,z},{z,z,z,z}};   // [i][vf]

    for (int st = 0; st < 16; ++st) {
        int s0g = sb*1024 + st*64;
        __syncthreads();   // prev tile's K/V reads done
        *(f16x8*)&Kh[sl0*72 + ch*8]      = pk[0];
        *(f16x8*)&Kh[(sl0+32)*72 + ch*8] = pk[1];
        *(f16x8*)&Vh[sl0*72 + ch*8]      = pv[0];
        *(f16x8*)&Vh[(sl0+32)*72 + ch*8] = pv[1];
        __syncthreads();   // staging visible
        if (st + 1 < 16) {
            int sn = s0g + 64;
            pk[0] = *(const f16x8*)&nkh[(size_t)(sn+sl0)*64 + ch*8];
            pk[1] = *(const f16x8*)&nkh[(size_t)(sn+sl0+32)*64 + ch*8];
            pv[0] = *(const f16x8*)&nvTh[(size_t)sl0*CAP + sn + ch*8];
            pv[1] = *(const f16x8*)&nvTh[(size_t)(sl0+32)*CAP + sn + ch*8];
        }
        // QK 2-term (q_hi + q_lo) x k_hi -> wave-private P
        #pragma unroll
        for (int cf = 0; cf < 4; ++cf) {
            int c0 = cf*16;
            f16x8 bh[2];
            #pragma unroll
            for (int t = 0; t < 2; ++t)
                bh[t] = *(const f16x8*)&Kh[(c0+lr)*72 + t*32 + lg*8];
            f32x4 qacc[2] = {z,z};
            #pragma unroll
            for (int i = 0; i < 2; ++i)
                #pragma unroll
                for (int t = 0; t < 2; ++t) {
                    qacc[i] = MF(ah[i][t], bh[t], qacc[i]);
                    qacc[i] = MF(al[i][t], bh[t], qacc[i]);
                }
            #pragma unroll
            for (int i = 0; i < 2; ++i)
                #pragma unroll
                for (int j = 0; j < 4; ++j) {
                    float a = __expf(qacc[i][j]) * iS[i][j];
                    Pw[(i*16 + lg*4 + j)*72 + c0 + lr] = (f16)a;
                }
        }
        // wave-internal LDS ordering: own P writes complete before reads
        asm volatile("s_waitcnt lgkmcnt(0)" ::: "memory");
        // PV (1-term), wave-private P rows, V from staged LDS
        f16x8 pah[2][2];
        #pragma unroll
        for (int i = 0; i < 2; ++i)
            #pragma unroll
            for (int t = 0; t < 2; ++t)
                pah[i][t] = *(const f16x8*)&Pw[(i*16 + lr)*72 + t*32 + lg*8];
        #pragma unroll
        for (int vf = 0; vf < 4; ++vf) {
            f16x8 vbh[2];
            #pragma unroll
            for (int t = 0; t < 2; ++t)
                vbh[t] = *(const f16x8*)&Vh[(vf*16 + lr)*72 + t*32 + lg*8];
            #pragma unroll
            for (int i = 0; i < 2; ++i)
                #pragma unroll
                for (int t = 0; t < 2; ++t)
                    pacc[i][vf] = MF(pah[i][t], vbh[t], pacc[i][vf]);
        }
        // att write from wave-private P: coalesced 256B row segments, through L2
        #pragma unroll
        for (int it = 0; it < 4; ++it) {
            int rloc = it*8 + (l >> 3);
            int k0 = (l & 7)*8;
            f16x8 ph = *(const f16x8*)&Pw[rloc*72 + k0];
            f32x4 lo = {(float)ph[0], (float)ph[1], (float)ph[2], (float)ph[3]};
            f32x4 hi = {(float)ph[4], (float)ph[5], (float)ph[6], (float)ph[7]};
            float* dst = &att[(size_t)(wrow0 + rloc)*CAP + s0g + k0];
            *(f32x4*)dst = lo;
            *(f32x4*)(dst + 4) = hi;
        }
    }
    #pragma unroll
    for (int i = 0; i < 2; ++i)
        #pragma unroll
        for (int vf = 0; vf < 4; ++vf)
            #pragma unroll
            for (int j = 0; j < 4; ++j) {
                int gr = wrow0 + i*16 + lg*4 + j;
                int gc = vf*16 + lr;
                ret_part[((size_t)sb*BATCH + gr)*64 + gc] = pacc[i][vf][j];
            }
}

// ---------------- reduce partial retrieved ----------------
__global__ void ret_reduce_kernel(const float* __restrict__ rp, float* __restrict__ out)
{
    int i4 = blockIdx.x*256 + threadIdx.x;   // BATCH*64/4 = 65536
    float4 s = {0.f,0.f,0.f,0.f};
    #pragma unroll
    for (int sb = 0; sb < 32; ++sb) {
        float4 p = ((const float4*)(rp + (size_t)sb*BATCH*64))[i4];
        s.x += p.x; s.y += p.y; s.z += p.z; s.w += p.w;
    }
    ((float4*)out)[i4] = s;
}

extern "C" void kernel_launch(void* const* d_in, const int* in_sizes, int n_in,
                              void* d_out, int out_size, void* d_ws, size_t ws_size,
                              hipStream_t stream) {
    const float* keys       = (const float*)d_in[0];
    const float* query      = (const float*)d_in[2];
    const float* mem_keys   = (const float*)d_in[3];
    const float* mem_values = (const float*)d_in[4];
    const float* Wk         = (const float*)d_in[5];
    const float* bk         = (const float*)d_in[6];
    const float* Wv         = (const float*)d_in[7];
    const float* bv         = (const float*)d_in[8];

    float* out = (float*)d_out;
    float* ret = out;                       // [4096,64]
    float* att = out + BATCH*64;            // [4096,32768]

    char* ws = (char*)d_ws;
    const size_t SK = (size_t)BATCH*64*2;   // 512 KB  f16 plane [4096][64]
    const size_t SC = (size_t)CAP*64*2;     // 4 MB    f16 plane [32768][64]
    f16* kph  = (f16*)(ws + 0*SK);
    f16* kpl  = (f16*)(ws + 1*SK);
    f16* svh  = (f16*)(ws + 2*SK);
    f16* qph  = (f16*)(ws + 3*SK);
    f16* qpl  = (f16*)(ws + 4*SK);
    size_t o = 5*SK;
    f16* nkh  = (f16*)(ws + o);            o += SC;
    f16* nvTh = (f16*)(ws + o);            o += SC;
    float* bestv  = (float*)(ws + o);      o += (size_t)BATCH*32*4;
    int*   besti  = (int*)(ws + o);        o += (size_t)BATCH*32*4;
    float* s_part = (float*)(ws + o);      o += (size_t)BATCH*64*4;
    int*   winner = (int*)(ws + o);        o += (size_t)CAP*4;
    float* ret_part = (float*)(ws + o);    // 32*4096*64*4 = 33.5 MB
    // mk planes overlaid on ret_part (disjoint lifetimes: sim vs pass2)
    f16* mkh = (f16*)ret_part;
    f16* mkl = (f16*)((char*)ret_part + SC);

    prep_kernel<<<768 + CAP*64/256, 256, 0, stream>>>(
        keys, query, Wk, bk, Wv, bv, mem_keys,
        kph, kpl, svh, qph, qpl, mkh, mkl, winner);
    sim_kernel<<<dim3(32, 32), 256, 0, stream>>>(kph, kpl, mkh, mkl, bestv, besti);
    argmax_scatter_kernel<<<BATCH/256, 256, 0, stream>>>(bestv, besti, winner);
    build_kernel<<<CAP/64, 256, 0, stream>>>(
        winner, kph, svh, mem_keys, mem_values, nkh, nvTh);
    logits_stats_kernel<<<dim3(64, 16), 256, 0, stream>>>(qph, nkh, s_part);
    pass2_kernel<<<dim3(32, 32), 256, 0, stream>>>(
        qph, qpl, nkh, nvTh, s_part, att, ret_part);
    ret_reduce_kernel<<<BATCH*64/4/256, 256, 0, stream>>>(ret_part, ret);
}

// Round 13
// 268.030 us; speedup vs baseline: 1.1609x; 1.1609x over previous
//
#include <hip/hip_runtime.h>
#include <math.h>
#include <float.h>

#define BATCH 4096
#define CAP   32768

typedef _Float16 f16;
typedef _Float16 f16x8 __attribute__((ext_vector_type(8)));
typedef float    f32x4 __attribute__((ext_vector_type(4)));
typedef unsigned long long u64;

__device__ __forceinline__ f32x4 MF(f16x8 a, f16x8 b, f32x4 c) {
    return __builtin_amdgcn_mfma_f32_16x16x32_f16(a, b, c, 0, 0, 0);
}

// order-preserving float->uint key (total order matches float compare for finite values)
__device__ __forceinline__ unsigned int fkey(float v) {
    unsigned int b = __float_as_uint(v);
    return (b & 0x80000000u) ? ~b : (b | 0x80000000u);
}

// ---------------- fused prep: projections + mem_keys split + winner/best init ----------------
__global__ __launch_bounds__(256) void prep_kernel(
    const float* __restrict__ keys, const float* __restrict__ query,
    const float* __restrict__ Wk, const float* __restrict__ bk,
    const float* __restrict__ Wv, const float* __restrict__ bv,
    const float* __restrict__ mk,
    f16* __restrict__ kph, f16* __restrict__ kpl,
    f16* __restrict__ svh,
    f16* __restrict__ qph, f16* __restrict__ qpl,
    f16* __restrict__ mkh, f16* __restrict__ mkl,
    int* __restrict__ winner, u64* __restrict__ best_packed)
{
    int bx = blockIdx.x;
    int tid = threadIdx.x;
    if (bx >= 768) {
        int i = (bx - 768)*256 + tid;    // CAP*64 elements
        float x = mk[i];
        f16 h = (f16)x;
        mkh[i] = h;
        mkl[i] = (f16)((x - (float)h) * 2048.0f);
        if (i < CAP) winner[i] = -1;
        if (i < BATCH) best_packed[i] = 0ull;
        return;
    }
    int job = bx >> 8;   // 0: keys@Wk->kp (scaled lo), 1: query@Wv->sv (hi only), 2: query@Wk->qp
    const float *in, *W, *b; f16 *oh, *ol; bool scaled;
    if (job == 0)      { in = keys;  W = Wk; b = bk; oh = kph; ol = kpl;     scaled = true;  }
    else if (job == 1) { in = query; W = Wv; b = bv; oh = svh; ol = nullptr; scaled = false; }
    else               { in = query; W = Wk; b = bk; oh = qph; ol = qpl;     scaled = false; }

    __shared__ float Wl[64*65];
    __shared__ float inl[16*65];
    __shared__ float bl[64];
    int row0 = (bx & 255) * 16;
    for (int i = tid; i < 4096; i += 256) { int r = i >> 6, c = i & 63; Wl[r*65+c] = W[i]; }
    for (int i = tid; i < 1024; i += 256) { int r = i >> 6, c = i & 63; inl[r*65+c] = in[(row0+r)*64 + c]; }
    if (tid < 64) bl[tid] = b[tid];
    __syncthreads();

    int col = tid & 63;
    int rq  = tid >> 6;
    #pragma unroll
    for (int q = 0; q < 4; ++q) {
        int r = rq*4 + q;
        float acc = bl[col];
        #pragma unroll
        for (int k = 0; k < 64; ++k) acc += inl[r*65+k] * Wl[col*65+k];
        float t = tanhf(acc);
        f16 h = (f16)t;
        oh[(row0+r)*64 + col] = h;
        if (ol) {
            float lo = t - (float)h;
            if (scaled) lo *= 2048.0f;
            ol[(row0+r)*64 + col] = (f16)lo;
        }
    }
}

// ---------------- sim = kp @ mem_keys.T via f16-split MFMA (3-term); packed-atomic argmax ----------------
// grid (32 sb x 1024 slots, 16 rb x 256 rows); block 256 = 4 waves x 64 rows  [r10 proven form]
__global__ __launch_bounds__(256, 2) void sim_kernel(
    const f16* __restrict__ Aph, const f16* __restrict__ Apl,
    const f16* __restrict__ Bph, const f16* __restrict__ Bpl,
    u64* __restrict__ best_packed)
{
    __shared__ __align__(16) f16 Bh[64*72], Bl[64*72];
    int tid = threadIdx.x, l = tid & 63, w = tid >> 6;
    int sb = blockIdx.x, rb = blockIdx.y;
    int row0 = rb*256 + w*64;
    int lr = l & 15, lg = l >> 4;
    int sl0 = tid >> 3, ch = tid & 7;

    f16x8 ah[4][2], al[4][2];
    #pragma unroll
    for (int i = 0; i < 4; ++i)
        #pragma unroll
        for (int t = 0; t < 2; ++t) {
            size_t o = (size_t)(row0 + i*16 + lr)*64 + t*32 + lg*8;
            ah[i][t] = *(const f16x8*)&Aph[o];
            al[i][t] = *(const f16x8*)&Apl[o];
        }
    float bvv[4][4]; int bii[4][4];
    #pragma unroll
    for (int i = 0; i < 4; ++i)
        #pragma unroll
        for (int j = 0; j < 4; ++j) { bvv[i][j] = -FLT_MAX; bii[i][j] = 0; }

    f16x8 pb[2][2];
    {
        int s0 = sb*1024;
        pb[0][0] = *(const f16x8*)&Bph[(size_t)(s0+sl0)*64 + ch*8];
        pb[0][1] = *(const f16x8*)&Bpl[(size_t)(s0+sl0)*64 + ch*8];
        pb[1][0] = *(const f16x8*)&Bph[(size_t)(s0+sl0+32)*64 + ch*8];
        pb[1][1] = *(const f16x8*)&Bpl[(size_t)(s0+sl0+32)*64 + ch*8];
    }

    for (int st = 0; st < 16; ++st) {
        int s0 = sb*1024 + st*64;
        __syncthreads();
        *(f16x8*)&Bh[sl0*72 + ch*8]      = pb[0][0];
        *(f16x8*)&Bl[sl0*72 + ch*8]      = pb[0][1];
        *(f16x8*)&Bh[(sl0+32)*72 + ch*8] = pb[1][0];
        *(f16x8*)&Bl[(sl0+32)*72 + ch*8] = pb[1][1];
        __syncthreads();
        if (st + 1 < 16) {
            int sn = s0 + 64;
            pb[0][0] = *(const f16x8*)&Bph[(size_t)(sn+sl0)*64 + ch*8];
            pb[0][1] = *(const f16x8*)&Bpl[(size_t)(sn+sl0)*64 + ch*8];
            pb[1][0] = *(const f16x8*)&Bph[(size_t)(sn+sl0+32)*64 + ch*8];
            pb[1][1] = *(const f16x8*)&Bpl[(size_t)(sn+sl0+32)*64 + ch*8];
        }
        #pragma unroll
        for (int cf = 0; cf < 4; ++cf) {
            int c0 = cf*16;
            f16x8 bh[2], bl2[2];
            #pragma unroll
            for (int t = 0; t < 2; ++t) {
                bh[t]  = *(const f16x8*)&Bh[(c0+lr)*72 + t*32 + lg*8];
                bl2[t] = *(const f16x8*)&Bl[(c0+lr)*72 + t*32 + lg*8];
            }
            f32x4 z = {0.f,0.f,0.f,0.f};
            f32x4 aA[4] = {z,z,z,z}, aB[4] = {z,z,z,z};
            #pragma unroll
            for (int i = 0; i < 4; ++i)
                #pragma unroll
                for (int t = 0; t < 2; ++t) {
                    aA[i] = MF(ah[i][t], bh[t],  aA[i]);
                    aB[i] = MF(ah[i][t], bl2[t], aB[i]);
                    aB[i] = MF(al[i][t], bh[t],  aB[i]);
                }
            int slot = s0 + c0 + lr;
            #pragma unroll
            for (int i = 0; i < 4; ++i)
                #pragma unroll
                for (int j = 0; j < 4; ++j) {
                    float v = aA[i][j] + aB[i][j]*(1.0f/2048.0f);
                    if (v > bvv[i][j]) { bvv[i][j] = v; bii[i][j] = slot; }
                }
        }
    }
    #pragma unroll
    for (int m = 1; m < 16; m <<= 1)
        #pragma unroll
        for (int i = 0; i < 4; ++i)
            #pragma unroll
            for (int j = 0; j < 4; ++j) {
                float ov = __shfl_xor(bvv[i][j], m);
                int   oi = __shfl_xor(bii[i][j], m);
                if (ov > bvv[i][j] || (ov == bvv[i][j] && oi < bii[i][j])) { bvv[i][j] = ov; bii[i][j] = oi; }
            }
    if (lr == 0) {
        #pragma unroll
        for (int i = 0; i < 4; ++i)
            #pragma unroll
            for (int j = 0; j < 4; ++j) {
                int r = row0 + i*16 + lg*4 + j;
                // pack: (ordered-key << 32) | ~slot ; max => max value, smallest slot on ties
                u64 p = ((u64)fkey(bvv[i][j]) << 32) | (unsigned int)(~(unsigned int)bii[i][j]);
                atomicMax(&best_packed[r], p);
            }
    }
}

// ---------------- winner scatter from packed argmax ----------------
__global__ void argmax_scatter_kernel(const u64* __restrict__ best_packed,
                                      int* __restrict__ winner)
{
    int r = blockIdx.x*256 + threadIdx.x;
    if (r >= BATCH) return;
    u64 p = best_packed[r];
    int slot = (int)(~(unsigned int)(p & 0xFFFFFFFFull));
    atomicMax(&winner[slot], r);   // last-write-wins == max batch index
}

// ---------------- build new_keys hi plane + transposed new_values (hi only) ----------------
__global__ __launch_bounds__(256) void build_kernel(
    const int* __restrict__ winner,
    const f16* __restrict__ kph,
    const f16* __restrict__ svh,
    const float* __restrict__ mk, const float* __restrict__ mv,
    f16* __restrict__ nkh,
    f16* __restrict__ nvTh)
{
    __shared__ __align__(16) f16 Lh[64*72];
    int tid = threadIdx.x;
    int s0 = blockIdx.x*64;
    #pragma unroll
    for (int c = 0; c < 2; ++c) {
        int task = tid + 256*c; int sl = task >> 3, ch = task & 7;
        int s = s0 + sl; int w = winner[s];
        f16x8 hk, hv;
        if (w >= 0) {
            hk = *(const f16x8*)&kph[(size_t)w*64 + ch*8];
            hv = *(const f16x8*)&svh[(size_t)w*64 + ch*8];
        } else {
            #pragma unroll
            for (int q = 0; q < 8; ++q) {
                hk[q] = (f16)mk[(size_t)s*64 + ch*8 + q];
                hv[q] = (f16)mv[(size_t)s*64 + ch*8 + q];
            }
        }
        *(f16x8*)&nkh[(size_t)s*64 + ch*8] = hk;
        *(f16x8*)&Lh[sl*72 + ch*8] = hv;
    }
    __syncthreads();
    int v = tid >> 2, sc = (tid & 3)*16;
    f16x8 a, b2;
    #pragma unroll
    for (int q = 0; q < 8; ++q) { a[q] = Lh[(sc+q)*72 + v]; b2[q] = Lh[(sc+8+q)*72 + v]; }
    *(f16x8*)&nvTh[(size_t)v*CAP + s0 + sc]     = a;
    *(f16x8*)&nvTh[(size_t)v*CAP + s0 + sc + 8] = b2;
}

// ---------------- pass1: denominator only. hh-only logits; S = sum exp(v) (no max shift) ----------------
// grid (64 sb x 512 slots, 8 rb x 512 rows); block 256 = 4 waves x 128 rows  [r10 proven form]
__global__ __launch_bounds__(256, 2) void logits_stats_kernel(
    const f16* __restrict__ Aph,
    const f16* __restrict__ Bph,
    float* __restrict__ s_part)
{
    __shared__ __align__(16) f16 Bh[64*72];
    int tid = threadIdx.x, l = tid & 63, w = tid >> 6;
    int sb = blockIdx.x, rb = blockIdx.y;
    int row0 = rb*512 + w*128;
    int lr = l & 15, lg = l >> 4;
    int sl0 = tid >> 3, ch = tid & 7;

    f16x8 ah[8][2];
    #pragma unroll
    for (int i = 0; i < 8; ++i)
        #pragma unroll
        for (int t = 0; t < 2; ++t)
            ah[i][t] = *(const f16x8*)&Aph[(size_t)(row0 + i*16 + lr)*64 + t*32 + lg*8];

    float ssum[8][4];
    #pragma unroll
    for (int i = 0; i < 8; ++i)
        #pragma unroll
        for (int j = 0; j < 4; ++j) ssum[i][j] = 0.f;

    f16x8 pb[2];
    {
        int s0 = sb*512;
        pb[0] = *(const f16x8*)&Bph[(size_t)(s0+sl0)*64 + ch*8];
        pb[1] = *(const f16x8*)&Bph[(size_t)(s0+sl0+32)*64 + ch*8];
    }

    for (int st = 0; st < 8; ++st) {
        int s0 = sb*512 + st*64;
        __syncthreads();
        *(f16x8*)&Bh[sl0*72 + ch*8]      = pb[0];
        *(f16x8*)&Bh[(sl0+32)*72 + ch*8] = pb[1];
        __syncthreads();
        if (st + 1 < 8) {
            int sn = s0 + 64;
            pb[0] = *(const f16x8*)&Bph[(size_t)(sn+sl0)*64 + ch*8];
            pb[1] = *(const f16x8*)&Bph[(size_t)(sn+sl0+32)*64 + ch*8];
        }
        #pragma unroll
        for (int cf = 0; cf < 4; ++cf) {
            int c0 = cf*16;
            f16x8 bh[2];
            #pragma unroll
            for (int t = 0; t < 2; ++t)
                bh[t] = *(const f16x8*)&Bh[(c0+lr)*72 + t*32 + lg*8];
            f32x4 z = {0.f,0.f,0.f,0.f};
            f32x4 acc[8] = {z,z,z,z,z,z,z,z};
            #pragma unroll
            for (int i = 0; i < 8; ++i) {
                acc[i] = MF(ah[i][0], bh[0], acc[i]);
                acc[i] = MF(ah[i][1], bh[1], acc[i]);
            }
            #pragma unroll
            for (int i = 0; i < 8; ++i)
                #pragma unroll
                for (int j = 0; j < 4; ++j)
                    ssum[i][j] += __expf(acc[i][j]);
        }
    }
    #pragma unroll
    for (int m = 1; m < 16; m <<= 1)
        #pragma unroll
        for (int i = 0; i < 8; ++i)
            #pragma unroll
            for (int j = 0; j < 4; ++j)
                ssum[i][j] += __shfl_xor(ssum[i][j], m);
    if (lr == 0) {
        #pragma unroll
        for (int i = 0; i < 8; ++i)
            #pragma unroll
            for (int j = 0; j < 4; ++j) {
                int r = row0 + i*16 + lg*4 + j;
                s_part[r*64 + sb] = ssum[i][j];
            }
    }
}

// ---------------- pass2: K/V staged + prefetch, wave-private P, 32-row waves ----------------
// grid (32 sb x 1024 slots, 32 rb x 128 rows); block 256 = 4 waves x 32 rows  [r10 proven form]
__global__ __launch_bounds__(256, 3) void pass2_kernel(
    const f16* __restrict__ qph, const f16* __restrict__ qpl,
    const f16* __restrict__ nkh,
    const f16* __restrict__ nvTh,
    const float* __restrict__ s_part,
    float* __restrict__ att, float* __restrict__ ret_part)
{
    __shared__ __align__(16) f16 Kh[64*72];
    __shared__ __align__(16) f16 Vh[64*72];
    __shared__ __align__(16) f16 Ph[4][32*72];   // wave-private P
    __shared__ float iSl[128];
    int tid = threadIdx.x, l = tid & 63, w = tid >> 6;
    int sb = blockIdx.x, rb = blockIdx.y;
    int brow0 = rb*128;
    int wrow0 = brow0 + w*32;
    int lr = l & 15, lg = l >> 4;
    int sl0 = tid >> 3, ch = tid & 7;
    f16* Pw = &Ph[w][0];

    // prologue: per-row denominator (2 threads/row)
    {
        int r_loc = tid >> 1, half = tid & 1;
        const float4* p = (const float4*)(s_part + (size_t)(brow0 + r_loc)*64 + half*32);
        float S = 0.f;
        #pragma unroll
        for (int q = 0; q < 8; ++q) {
            float4 v = p[q];
            S += (v.x + v.y) + (v.z + v.w);
        }
        S += __shfl_xor(S, 1);
        if (!half) iSl[r_loc] = 1.0f / S;
    }

    f16x8 ah[2][2], al[2][2];
    #pragma unroll
    for (int i = 0; i < 2; ++i)
        #pragma unroll
        for (int t = 0; t < 2; ++t) {
            size_t o = (size_t)(wrow0 + i*16 + lr)*64 + t*32 + lg*8;
            ah[i][t] = *(const f16x8*)&qph[o];
            al[i][t] = *(const f16x8*)&qpl[o];
        }
    f16x8 pk[2], pv[2];
    {
        int s0g = sb*1024;
        pk[0] = *(const f16x8*)&nkh[(size_t)(s0g+sl0)*64 + ch*8];
        pk[1] = *(const f16x8*)&nkh[(size_t)(s0g+sl0+32)*64 + ch*8];
        pv[0] = *(const f16x8*)&nvTh[(size_t)sl0*CAP + s0g + ch*8];
        pv[1] = *(const f16x8*)&nvTh[(size_t)(sl0+32)*CAP + s0g + ch*8];
    }
    __syncthreads();   // iSl visible
    float iS[2][4];
    #pragma unroll
    for (int i = 0; i < 2; ++i)
        #pragma unroll
        for (int j = 0; j < 4; ++j)
            iS[i][j] = iSl[w*32 + i*16 + lg*4 + j];

    f32x4 z = {0.f,0.f,0.f,0.f};
    f32x4 pacc[2][4] = {{z,z,z,z},{z,z,z,z}};   // [i][vf]

    for (int st = 0; st < 16; ++st) {
        int s0g = sb*1024 + st*64;
        __syncthreads();   // prev tile's K/V reads done
        *(f16x8*)&Kh[sl0*72 + ch*8]      = pk[0];
        *(f16x8*)&Kh[(sl0+32)*72 + ch*8] = pk[1];
        *(f16x8*)&Vh[sl0*72 + ch*8]      = pv[0];
        *(f16x8*)&Vh[(sl0+32)*72 + ch*8] = pv[1];
        __syncthreads();   // staging visible
        if (st + 1 < 16) {
            int sn = s0g + 64;
            pk[0] = *(const f16x8*)&nkh[(size_t)(sn+sl0)*64 + ch*8];
            pk[1] = *(const f16x8*)&nkh[(size_t)(sn+sl0+32)*64 + ch*8];
            pv[0] = *(const f16x8*)&nvTh[(size_t)sl0*CAP + sn + ch*8];
            pv[1] = *(const f16x8*)&nvTh[(size_t)(sl0+32)*CAP + sn + ch*8];
        }
        // QK 2-term (q_hi + q_lo) x k_hi -> wave-private P
        #pragma unroll
        for (int cf = 0; cf < 4; ++cf) {
            int c0 = cf*16;
            f16x8 bh[2];
            #pragma unroll
            for (int t = 0; t < 2; ++t)
                bh[t] = *(const f16x8*)&Kh[(c0+lr)*72 + t*32 + lg*8];
            f32x4 qacc[2] = {z,z};
            #pragma unroll
            for (int i = 0; i < 2; ++i)
                #pragma unroll
                for (int t = 0; t < 2; ++t) {
                    qacc[i] = MF(ah[i][t], bh[t], qacc[i]);
                    qacc[i] = MF(al[i][t], bh[t], qacc[i]);
                }
            #pragma unroll
            for (int i = 0; i < 2; ++i)
                #pragma unroll
                for (int j = 0; j < 4; ++j) {
                    float a = __expf(qacc[i][j]) * iS[i][j];
                    Pw[(i*16 + lg*4 + j)*72 + c0 + lr] = (f16)a;
                }
        }
        // wave-internal LDS ordering: own P writes complete before reads
        asm volatile("s_waitcnt lgkmcnt(0)" ::: "memory");
        // PV (1-term), wave-private P rows, V from staged LDS
        f16x8 pah[2][2];
        #pragma unroll
        for (int i = 0; i < 2; ++i)
            #pragma unroll
            for (int t = 0; t < 2; ++t)
                pah[i][t] = *(const f16x8*)&Pw[(i*16 + lr)*72 + t*32 + lg*8];
        #pragma unroll
        for (int vf = 0; vf < 4; ++vf) {
            f16x8 vbh[2];
            #pragma unroll
            for (int t = 0; t < 2; ++t)
                vbh[t] = *(const f16x8*)&Vh[(vf*16 + lr)*72 + t*32 + lg*8];
            #pragma unroll
            for (int i = 0; i < 2; ++i)
                #pragma unroll
                for (int t = 0; t < 2; ++t)
                    pacc[i][vf] = MF(pah[i][t], vbh[t], pacc[i][vf]);
        }
        // att write from wave-private P: coalesced 256B row segments, through L2
        #pragma unroll
        for (int it = 0; it < 4; ++it) {
            int rloc = it*8 + (l >> 3);
            int k0 = (l & 7)*8;
            f16x8 ph = *(const f16x8*)&Pw[rloc*72 + k0];
            f32x4 lo = {(float)ph[0], (float)ph[1], (float)ph[2], (float)ph[3]};
            f32x4 hi = {(float)ph[4], (float)ph[5], (float)ph[6], (float)ph[7]};
            float* dst = &att[(size_t)(wrow0 + rloc)*CAP + s0g + k0];
            *(f32x4*)dst = lo;
            *(f32x4*)(dst + 4) = hi;
        }
    }
    #pragma unroll
    for (int i = 0; i < 2; ++i)
        #pragma unroll
        for (int vf = 0; vf < 4; ++vf)
            #pragma unroll
            for (int j = 0; j < 4; ++j) {
                int gr = wrow0 + i*16 + lg*4 + j;
                int gc = vf*16 + lr;
                ret_part[((size_t)sb*BATCH + gr)*64 + gc] = pacc[i][vf][j];
            }
}

// ---------------- reduce partial retrieved ----------------
__global__ void ret_reduce_kernel(const float* __restrict__ rp, float* __restrict__ out)
{
    int i4 = blockIdx.x*256 + threadIdx.x;   // BATCH*64/4 = 65536
    float4 s = {0.f,0.f,0.f,0.f};
    #pragma unroll
    for (int sb = 0; sb < 32; ++sb) {
        float4 p = ((const float4*)(rp + (size_t)sb*BATCH*64))[i4];
        s.x += p.x; s.y += p.y; s.z += p.z; s.w += p.w;
    }
    ((float4*)out)[i4] = s;
}

extern "C" void kernel_launch(void* const* d_in, const int* in_sizes, int n_in,
                              void* d_out, int out_size, void* d_ws, size_t ws_size,
                              hipStream_t stream) {
    const float* keys       = (const float*)d_in[0];
    const float* query      = (const float*)d_in[2];
    const float* mem_keys   = (const float*)d_in[3];
    const float* mem_values = (const float*)d_in[4];
    const float* Wk         = (const float*)d_in[5];
    const float* bk         = (const float*)d_in[6];
    const float* Wv         = (const float*)d_in[7];
    const float* bv         = (const float*)d_in[8];

    float* out = (float*)d_out;
    float* ret = out;                       // [4096,64]
    float* att = out + BATCH*64;            // [4096,32768]

    char* ws = (char*)d_ws;
    const size_t SK = (size_t)BATCH*64*2;   // 512 KB  f16 plane [4096][64]
    const size_t SC = (size_t)CAP*64*2;     // 4 MB    f16 plane [32768][64]
    f16* kph  = (f16*)(ws + 0*SK);
    f16* kpl  = (f16*)(ws + 1*SK);
    f16* svh  = (f16*)(ws + 2*SK);
    f16* qph  = (f16*)(ws + 3*SK);
    f16* qpl  = (f16*)(ws + 4*SK);
    size_t o = 5*SK;
    f16* nkh  = (f16*)(ws + o);            o += SC;
    f16* nvTh = (f16*)(ws + o);            o += SC;
    u64* best_packed = (u64*)(ws + o);     o += (size_t)BATCH*8;
    float* s_part = (float*)(ws + o);      o += (size_t)BATCH*64*4;
    int*   winner = (int*)(ws + o);        o += (size_t)CAP*4;
    float* ret_part = (float*)(ws + o);    // 32*4096*64*4 = 33.5 MB
    // mk planes overlaid on ret_part (disjoint lifetimes: sim vs pass2)
    f16* mkh = (f16*)ret_part;
    f16* mkl = (f16*)((char*)ret_part + SC);

    prep_kernel<<<768 + CAP*64/256, 256, 0, stream>>>(
        keys, query, Wk, bk, Wv, bv, mem_keys,
        kph, kpl, svh, qph, qpl, mkh, mkl, winner, best_packed);
    sim_kernel<<<dim3(32, 16), 256, 0, stream>>>(kph, kpl, mkh, mkl, best_packed);
    argmax_scatter_kernel<<<BATCH/256, 256, 0, stream>>>(best_packed, winner);
    build_kernel<<<CAP/64, 256, 0, stream>>>(
        winner, kph, svh, mem_keys, mem_values, nkh, nvTh);
    logits_stats_kernel<<<dim3(64, 8), 256, 0, stream>>>(qph, nkh, s_part);
    pass2_kernel<<<dim3(32, 32), 256, 0, stream>>>(
        qph, qpl, nkh, nvTh, s_part, att, ret_part);
    ret_reduce_kernel<<<BATCH*64/4/256, 256, 0, stream>>>(ret_part, ret);
}